// Round 2
// baseline (1810.688 us; speedup 1.0000x reference)
//
#include <hip/hip_runtime.h>

// Correlation: out[b,(dy+4)*9+(dx+4),y,x] = (1/C) sum_c first[b,c,y,x]*second[b,c,y+dy,x+dx]
//
// R2: 256-thread blocks. dy split 3-ways over gridDim.z (acc = 3*9*4 = 108/thread).
// Within a block, channels split even/odd across two 128-thread halves (cs) ->
// 4 waves/block, 720 blocks -> 11.25 waves/CU. Deep pipeline: staging tile and
// first-values prefetched into registers one full iteration (2 channels) ahead;
// ONE barrier per 2 channels. Cross-half acc reduction via LDS at the end.

constexpr int Bn = 8;
constexpr int Cn = 128;
constexpr int Hn = 96;
constexpr int Wn = 160;
constexpr int CHS = Hn * Wn;

constexpr int TW = 32, TH = 16;
constexpr int NT = 256;
constexpr int HR = TH + 2;          // 18 halo rows
constexpr int HC4 = 12;             // float4 chunks per row (origin x0-8)
constexpr int PITCH = 48;
constexpr int SLOTS = HR * HC4;     // 216 per channel
constexpr int SLOTS2 = 2 * SLOTS;   // 432 per channel-pair
constexpr int CTILE = HR * PITCH;   // 864 floats per channel tile
constexpr int XSTRIDE = 37;         // exchange stride (bank-spread)
constexpr int LDSF = 128 * XSTRIDE + 40;  // 4776 >= 4*CTILE (3456)

__global__ __launch_bounds__(NT, 3)
void corr3(const float* __restrict__ first,
           const float* __restrict__ second,
           float* __restrict__ out)
{
    __shared__ float lds[LDSF];

    const int tid = threadIdx.x;
    const int cs  = tid >> 7;        // channel half: 0 = even ch, 1 = odd ch
    const int t   = tid & 127;
    const int tx  = t & 7;           // 4 px each -> 32 px
    const int ty  = t >> 3;          // 0..15
    const int x0  = blockIdx.x * TW;
    const int y0  = blockIdx.y * TH;
    const int b   = blockIdx.z / 3;
    const int g   = blockIdx.z % 3;  // dy' = 3g + d
    const int row0 = y0 + 3 * g - 4;

    // staging: 432 float4 slots (2 channels x 18 rows x 12 chunks), 256 threads
    const int e0 = tid, e1 = tid + NT;
    const int ch0 = e0 / SLOTS, s0 = e0 % SLOTS;
    const int ch1 = e1 / SLOTS, s1 = e1 % SLOTS;
    const int r0s = s0 / HC4, c40 = s0 % HC4;
    const int r1s = s1 / HC4, c41 = s1 % HC4;
    const int gy0 = row0 + r0s, gy1 = row0 + r1s;
    const int gx0 = x0 - 8 + c40 * 4, gx1 = x0 - 8 + c41 * 4;
    const bool s1ok = (e1 < SLOTS2);
    const bool v0 = (gy0 >= 0) & (gy0 < Hn) & (gx0 >= 0) & (gx0 < Wn);
    const bool v1 = s1ok & (gy1 >= 0) & (gy1 < Hn) & (gx1 >= 0) & (gx1 < Wn);
    const int go0 = ch0 * CHS + gy0 * Wn + gx0;   // used only when v0
    const int go1 = ch1 * CHS + gy1 * Wn + gx1;
    const int lo0 = ch0 * CTILE + r0s * PITCH + c40 * 4;
    const int lo1 = ch1 * CTILE + r1s * PITCH + c41 * 4;

    const float* secb = second + (size_t)b * Cn * CHS;
    const float* fb   = first  + (size_t)b * Cn * CHS + (y0 + ty) * Wn + x0 + tx * 4;

    float acc[3][9][4] = {};

    float4 sa, sb;   // staging prefetch regs (one channel-pair)
    float4 f;        // first prefetch reg

    // prologue: stage pair(0,1) to buf0; prefetch pair(2,3) + fv(ch cs)
    {
        sa = make_float4(0.f, 0.f, 0.f, 0.f);
        sb = make_float4(0.f, 0.f, 0.f, 0.f);
        if (v0) sa = *(const float4*)(secb + go0);
        if (v1) sb = *(const float4*)(secb + go1);
        *(float4*)&lds[lo0] = sa;
        if (s1ok) *(float4*)&lds[lo1] = sb;

        sa = make_float4(0.f, 0.f, 0.f, 0.f);
        sb = make_float4(0.f, 0.f, 0.f, 0.f);
        const float* p2 = secb + 2 * CHS;
        if (v0) sa = *(const float4*)(p2 + go0);
        if (v1) sb = *(const float4*)(p2 + go1);

        f = *(const float4*)(fb + (size_t)cs * CHS);
    }
    __syncthreads();

    #pragma unroll 1
    for (int c = 0; c < Cn; c += 2) {
        const int buf = (c >> 1) & 1;

        // drain staging regs (pair c+2) into the other buffer
        if (c + 2 < Cn) {
            const int off = (buf ^ 1) * (2 * CTILE);
            *(float4*)&lds[off + lo0] = sa;
            if (s1ok) *(float4*)&lds[off + lo1] = sb;
        }
        // issue staging loads for pair c+4 (consumed next iteration)
        if (c + 4 < Cn) {
            sa = make_float4(0.f, 0.f, 0.f, 0.f);
            sb = make_float4(0.f, 0.f, 0.f, 0.f);
            const float* p = secb + (c + 4) * CHS;
            if (v0) sa = *(const float4*)(p + go0);
            if (v1) sb = *(const float4*)(p + go1);
        }
        // fv for this channel (prefetched); issue next fv
        const float4 fv = f;
        if (c + 2 < Cn) f = *(const float4*)(fb + (size_t)(c + 2 + cs) * CHS);
        const float fa[4] = {fv.x, fv.y, fv.z, fv.w};

        const float* base = &lds[buf * (2 * CTILE) + cs * CTILE];
        #pragma unroll
        for (int d = 0; d < 3; ++d) {
            const float* rp = base + (ty + d) * PITCH + tx * 4 + 4;
            float4 w0 = *(const float4*)(rp + 0);
            float4 w1 = *(const float4*)(rp + 4);
            float4 w2 = *(const float4*)(rp + 8);
            const float w[12] = {w0.x, w0.y, w0.z, w0.w,
                                 w1.x, w1.y, w1.z, w1.w,
                                 w2.x, w2.y, w2.z, w2.w};
            #pragma unroll
            for (int dx = 0; dx < 9; ++dx)
                #pragma unroll
                for (int p = 0; p < 4; ++p)
                    acc[d][dx][p] = fmaf(fa[p], w[dx + p], acc[d][dx][p]);
        }
        __syncthreads();
    }

    // ---- cross-half reduction + store ----
    const float invc = 1.0f / (float)Cn;
    float* ob = out + (size_t)b * 81 * CHS + (y0 + ty) * Wn + x0 + tx * 4;
    #pragma unroll 1
    for (int d = 0; d < 3; ++d) {
        if (cs == 1) {
            #pragma unroll
            for (int dx = 0; dx < 9; ++dx)
                #pragma unroll
                for (int p = 0; p < 4; ++p)
                    lds[t * XSTRIDE + dx * 4 + p] = acc[d][dx][p];
        }
        __syncthreads();
        if (cs == 0) {
            #pragma unroll
            for (int dx = 0; dx < 9; ++dx) {
                const int chn = (3 * g + d) * 9 + dx;
                float4 o;
                o.x = (acc[d][dx][0] + lds[t * XSTRIDE + dx * 4 + 0]) * invc;
                o.y = (acc[d][dx][1] + lds[t * XSTRIDE + dx * 4 + 1]) * invc;
                o.z = (acc[d][dx][2] + lds[t * XSTRIDE + dx * 4 + 2]) * invc;
                o.w = (acc[d][dx][3] + lds[t * XSTRIDE + dx * 4 + 3]) * invc;
                *(float4*)(ob + (size_t)chn * CHS) = o;
            }
        }
        __syncthreads();
    }
}

extern "C" void kernel_launch(void* const* d_in, const int* in_sizes, int n_in,
                              void* d_out, int out_size, void* d_ws, size_t ws_size,
                              hipStream_t stream) {
    const float* first  = (const float*)d_in[0];
    const float* second = (const float*)d_in[1];
    float* out = (float*)d_out;

    dim3 grid(Wn / TW, Hn / TH, Bn * 3);   // (5, 6, 24) = 720 blocks x 256 thr
    corr3<<<grid, dim3(NT, 1, 1), 0, stream>>>(first, second, out);
}

// Round 3
// 360.649 us; speedup vs baseline: 5.0206x; 5.0206x over previous
//
#include <hip/hip_runtime.h>

// Correlation: out[b,(dy+4)*9+(dx+4),y,x] = (1/C) sum_c first[b,c,y,x]*second[b,c,y+dy,x+dx]
//
// R3: dy split into 9 groups of ONE dy per block -> acc[9][4]=36 regs/thread,
// 2160 blocks x 2 waves = 16.9 waves/CU resident (R1 was 5.6 -> latency-bound).
// g is the fastest-varying grid dim so the 9 blocks sharing a tile's data are
// dispatch-adjacent (L2/L3 temporal locality for the 9x logical re-read).
// Depth-2 register prefetch of staging + first; one barrier per channel.
// PITCH=52 (16B-aligned rows; 52 mod 32 = 20 -> bank-spread, fixes R1's 6.6M
// conflicts at PITCH=48).
// LESSON (R2): never index acc[] with a non-unrolled loop var -> scratch demotion.

constexpr int Bn = 8;
constexpr int Cn = 128;
constexpr int Hn = 96;
constexpr int Wn = 160;
constexpr int CHS = Hn * Wn;

constexpr int TW = 32, TH = 16;
constexpr int NT = 128;             // 8 tx (4 px each) x 16 ty
constexpr int HR = TH;              // 16 halo rows (single dy per block)
constexpr int HC4 = 12;             // float4 chunks per row (48 floats, origin x0-8)
constexpr int PITCH = 52;           // words per LDS row (16B-aligned, bank-spread)
constexpr int SLOTS = HR * HC4;     // 192 staging slots per channel
constexpr int CT = HR * PITCH;      // 832 floats per channel buffer

__global__ __launch_bounds__(NT, 4)
void corr9(const float* __restrict__ first,
           const float* __restrict__ second,
           float* __restrict__ out)
{
    __shared__ float lds[2 * CT];   // 6.5 KB

    const int tid = threadIdx.x;
    const int tx  = tid & 7;        // 0..7, 4 px each
    const int ty  = tid >> 3;       // 0..15
    const int gx  = blockIdx.x;
    const int g   = gx % 9;         // dy' = g  (dy = g-4), fastest-varying
    const int x0  = (gx / 9) * TW;
    const int y0  = blockIdx.y * TH;
    const int b   = blockIdx.z;
    const int row0 = y0 + g - 4;    // global row of LDS row 0

    // staging: 192 float4 slots, 128 threads (thread<64 takes a 2nd slot)
    const int e0 = tid, e1 = tid + NT;
    const bool s1ok = (e1 < SLOTS);             // tid < 64
    const int r0 = e0 / HC4, c0 = e0 % HC4;
    const int r1 = e1 / HC4, c1 = e1 % HC4;
    const int gy0 = row0 + r0, gy1 = row0 + r1;
    const int gxx0 = x0 - 8 + c0 * 4, gxx1 = x0 - 8 + c1 * 4;
    // chunks are 4-aligned and W%4==0 -> all-in or all-out
    const bool v0 = (gy0 >= 0) & (gy0 < Hn) & (gxx0 >= 0) & (gxx0 < Wn);
    const bool v1 = s1ok & (gy1 >= 0) & (gy1 < Hn) & (gxx1 >= 0) & (gxx1 < Wn);
    const int go0 = gy0 * Wn + gxx0;
    const int go1 = gy1 * Wn + gxx1;
    const int lo0 = r0 * PITCH + c0 * 4;
    const int lo1 = r1 * PITCH + c1 * 4;

    const float* secb = second + (size_t)b * Cn * CHS;
    const float* fb   = first  + (size_t)b * Cn * CHS + (y0 + ty) * Wn + x0 + tx * 4;

    float acc[9][4] = {};

    float4 sa0, sb0, sa1, sb1;      // staging prefetch (ch c+1, c+2)
    float4 f0, f1;                  // first prefetch  (ch c,   c+1)

    // prologue: ch0 -> buf0 directly; prefetch ch1,ch2 staging; fv(0),fv(1)
    {
        float4 a = make_float4(0.f, 0.f, 0.f, 0.f);
        float4 bb = make_float4(0.f, 0.f, 0.f, 0.f);
        if (v0) a  = *(const float4*)(secb + go0);
        if (v1) bb = *(const float4*)(secb + go1);
        *(float4*)&lds[lo0] = a;
        if (s1ok) *(float4*)&lds[lo1] = bb;

        sa0 = make_float4(0.f, 0.f, 0.f, 0.f);
        sb0 = make_float4(0.f, 0.f, 0.f, 0.f);
        sa1 = make_float4(0.f, 0.f, 0.f, 0.f);
        sb1 = make_float4(0.f, 0.f, 0.f, 0.f);
        if (v0) sa0 = *(const float4*)(secb + 1 * CHS + go0);
        if (v1) sb0 = *(const float4*)(secb + 1 * CHS + go1);
        if (v0) sa1 = *(const float4*)(secb + 2 * CHS + go0);
        if (v1) sb1 = *(const float4*)(secb + 2 * CHS + go1);

        f0 = *(const float4*)(fb + 0 * CHS);
        f1 = *(const float4*)(fb + 1 * CHS);
    }
    __syncthreads();

    #pragma unroll 2
    for (int c = 0; c < Cn; ++c) {
        const int buf = c & 1;

        // drain ch c+1 staging regs into the other buffer
        if (c + 1 < Cn) {
            *(float4*)&lds[(buf ^ 1) * CT + lo0] = sa0;
            if (s1ok) *(float4*)&lds[(buf ^ 1) * CT + lo1] = sb0;
        }
        sa0 = sa1; sb0 = sb1;
        // issue staging loads for ch c+3 (LDS-written at iter c+2)
        if (c + 3 < Cn) {
            sa1 = make_float4(0.f, 0.f, 0.f, 0.f);
            sb1 = make_float4(0.f, 0.f, 0.f, 0.f);
            const float* p = secb + (c + 3) * CHS;
            if (v0) sa1 = *(const float4*)(p + go0);
            if (v1) sb1 = *(const float4*)(p + go1);
        }
        // first-value pipeline
        const float4 fv = f0;
        f0 = f1;
        if (c + 2 < Cn) f1 = *(const float4*)(fb + (size_t)(c + 2) * CHS);
        const float fa[4] = {fv.x, fv.y, fv.z, fv.w};

        // compute: one dy row, 12-float window, 36 FMAs
        const float* rp = &lds[buf * CT + ty * PITCH + tx * 4 + 4];
        float4 w0 = *(const float4*)(rp + 0);
        float4 w1 = *(const float4*)(rp + 4);
        float4 w2 = *(const float4*)(rp + 8);
        const float w[12] = {w0.x, w0.y, w0.z, w0.w,
                             w1.x, w1.y, w1.z, w1.w,
                             w2.x, w2.y, w2.z, w2.w};
        #pragma unroll
        for (int dx = 0; dx < 9; ++dx)
            #pragma unroll
            for (int p = 0; p < 4; ++p)
                acc[dx][p] = fmaf(fa[p], w[dx + p], acc[dx][p]);

        __syncthreads();
    }

    // epilogue — FULLY unrolled (acc must never be dynamically indexed)
    const float invc = 1.0f / (float)Cn;
    float* ob = out + (size_t)b * 81 * CHS + (y0 + ty) * Wn + x0 + tx * 4;
    #pragma unroll
    for (int dx = 0; dx < 9; ++dx) {
        const int chn = g * 9 + dx;
        float4 o = make_float4(acc[dx][0] * invc,
                               acc[dx][1] * invc,
                               acc[dx][2] * invc,
                               acc[dx][3] * invc);
        *(float4*)(ob + (size_t)chn * CHS) = o;
    }
}

extern "C" void kernel_launch(void* const* d_in, const int* in_sizes, int n_in,
                              void* d_out, int out_size, void* d_ws, size_t ws_size,
                              hipStream_t stream) {
    const float* first  = (const float*)d_in[0];
    const float* second = (const float*)d_in[1];
    float* out = (float*)d_out;

    dim3 grid(9 * (Wn / TW), Hn / TH, Bn);   // (45, 6, 8) = 2160 blocks
    corr9<<<grid, dim3(NT, 1, 1), 0, stream>>>(first, second, out);
}

// Round 4
// 218.650 us; speedup vs baseline: 8.2812x; 1.6494x over previous
//
#include <hip/hip_runtime.h>
#include <stdint.h>

// Correlation via MFMA. out[b,(dy+4)*9+(dx+4),y,x] = (1/128) sum_c F[c,y,x]*S[c,y+dy,x+dx]
//
// R4: two kernels.
//  1) prepass: second fp32 [b][c][h][w] -> channel-last bf16 "secp"
//     [b][yp=104][xp=176][128ch] in d_ws, halos zero-filled (y in -4..99, x in -8..167).
//  2) main: per block (xtile 32px, 8 rows, b): 16 waves; wave = (strip s, row r).
//     K-chunks of 32 ch staged in LDS as [16 rows][48 px][4 octs] (oct = 8 bf16 = 16B),
//     XOR-swizzled oct position ((q+x+(x>>2))&3) -> 2-way-max banks on write & read.
//     A-frags (first) gathered fp32->bf16 from global once per wave (reused over 9 dy).
//     D[m,n] band -> 9 dx channels; dy from staged row select. acc = 9*2*4 = 72 VGPR.
// LESSON (R2): acc[] only ever indexed by fully-unrolled loop vars.
// Fallback: if ws_size < 37.5 MB, run the R1 VALU kernel (verified 135 us).

typedef __attribute__((ext_vector_type(8))) short bf16x8;
typedef __attribute__((ext_vector_type(4))) float f32x4;

constexpr int Bn = 8, Cn = 128, Hn = 96, Wn = 160;
constexpr int CHS = Hn * Wn;
constexpr int YP = Hn + 8;          // 104 padded rows  (y = yp-4)
constexpr int XPD = Wn + 16;        // 176 padded px    (x = xp-8)
constexpr size_t SECP_OCTS = (size_t)Bn * YP * XPD * 16;  // uint4 units
constexpr size_t SECP_BYTES = SECP_OCTS * 16;             // 37,486,592 B

__device__ __forceinline__ uint32_t bf16rne(float f) {
    uint32_t u = __float_as_uint(f);
    return (u + 0x7FFFu + ((u >> 16) & 1u)) >> 16;
}
__device__ __forceinline__ uint32_t pk(float a, float b) {
    return bf16rne(a) | (bf16rne(b) << 16);
}

// ---------------- prepass: transpose+convert second to channel-last bf16 ----
__global__ __launch_bounds__(256)
void prepass(const float* __restrict__ sec, uint4* __restrict__ secp)
{
    __shared__ float xfer[80 * 130];   // [x-local][c], pitch 130 (41.6 KB)
    const int h   = blockIdx.x;        // x half: 0 or 1
    const int yp  = blockIdx.y;
    const int b   = blockIdx.z;
    const int y   = yp - 4;
    const int tid = threadIdx.x;
    const bool live = (y >= 0) && (y < Hn);

    if (live) {
        const float* src = sec + (size_t)b * Cn * CHS + (size_t)y * Wn + h * 80;
        #pragma unroll
        for (int i = 0; i < 10; ++i) {
            int e = tid + i * 256;                 // 2560 float4 = 128c x 20
            int c = e / 20, x4 = e % 20;
            float4 v = *(const float4*)(src + (size_t)c * CHS + 4 * x4);
            float* d = &xfer[(4 * x4) * 130 + c];
            d[0] = v.x; d[130] = v.y; d[260] = v.z; d[390] = v.w;
        }
    }
    __syncthreads();

    uint4* dst = secp + ((size_t)(b * YP + yp) * XPD) * 16;
    #pragma unroll
    for (int i = 0; i < 6; ++i) {
        int e = tid + i * 256;                     // 88 px * 16 octs = 1408
        if (e < 88 * 16) {
            int oc = e & 15, xq = e >> 4;
            int xp = h * 88 + xq;
            int x  = xp - 8;
            uint4 o = make_uint4(0u, 0u, 0u, 0u);
            if (live && x >= 0 && x < Wn) {
                const float* p = &xfer[(x - h * 80) * 130 + 8 * oc];
                o.x = pk(p[0], p[1]); o.y = pk(p[2], p[3]);
                o.z = pk(p[4], p[5]); o.w = pk(p[6], p[7]);
            }
            dst[(size_t)xp * 16 + oc] = o;
        }
    }
}

// ---------------- main MFMA kernel ----------------
__global__ __launch_bounds__(1024)
void corrmfma(const float* __restrict__ first, const uint4* __restrict__ secp,
              float* __restrict__ out)
{
    __shared__ uint4 smem[16 * 48 * 4];   // 48 KB: [row][xw][4 swizzled octs]

    const int tid  = threadIdx.x;
    const int w    = tid >> 6;
    const int lane = tid & 63;
    const int quad = lane >> 4;
    const int n16  = lane & 15;
    const int s    = w & 1;               // strip within tile
    const int r    = w >> 1;              // output row within group
    const int x0   = blockIdx.x * 32;
    const int y0   = blockIdx.y * 8;
    const int b    = blockIdx.z;
    const int y    = y0 + r;
    const int x0s  = x0 + 16 * s;

    // ---- A-frags: first[b][32kc+8quad+j][y][x0s+n16], packed bf16 ----
    bf16x8 aF[4];
    {
        const float* fp = first + (size_t)b * Cn * CHS + (size_t)y * Wn + x0s + n16;
        #pragma unroll
        for (int kc = 0; kc < 4; ++kc) {
            float f[8];
            #pragma unroll
            for (int j = 0; j < 8; ++j)
                f[j] = fp[(size_t)(32 * kc + 8 * quad + j) * CHS];
            union { uint32_t u[4]; bf16x8 v; } cv;
            cv.u[0] = pk(f[0], f[1]); cv.u[1] = pk(f[2], f[3]);
            cv.u[2] = pk(f[4], f[5]); cv.u[3] = pk(f[6], f[7]);
            aF[kc] = cv.v;
        }
    }

    // ---- staging descriptors: 3072 octs (16 rows x 48 px x 4 octs) ----
    const uint4* sb = secp + (size_t)b * YP * XPD * 16;
    int gbase[3], lpos[3];
    #pragma unroll
    for (int i = 0; i < 3; ++i) {
        int e = tid + i * 1024;
        int row = e / 192, rem = e % 192;
        int xw = rem >> 2, q = rem & 3;
        gbase[i] = ((y0 + row) * XPD + (x0 + xw)) * 16 + q;       // + 4*kc later
        lpos[i]  = (row * 48 + xw) * 4 + ((q + xw + (xw >> 2)) & 3);
    }

    // ---- B-frag lane offsets (row-invariant part) ----
    int bo[2];
    #pragma unroll
    for (int t = 0; t < 2; ++t) {
        int xwr = 16 * (s + t) + n16;
        bo[t] = xwr * 4 + ((quad + xwr + (xwr >> 2)) & 3);
    }

    f32x4 acc[9][2];
    #pragma unroll
    for (int dy = 0; dy < 9; ++dy)
        #pragma unroll
        for (int t = 0; t < 2; ++t)
            acc[dy][t] = (f32x4){0.f, 0.f, 0.f, 0.f};

    // prologue: loads for chunk 0
    uint4 st[3];
    #pragma unroll
    for (int i = 0; i < 3; ++i) st[i] = sb[gbase[i]];

    #pragma unroll
    for (int kc = 0; kc < 4; ++kc) {
        #pragma unroll
        for (int i = 0; i < 3; ++i) smem[lpos[i]] = st[i];
        __syncthreads();
        if (kc < 3) {
            #pragma unroll
            for (int i = 0; i < 3; ++i) st[i] = sb[gbase[i] + 4 * (kc + 1)];
        }
        #pragma unroll
        for (int dy = 0; dy < 9; ++dy) {
            const int rb = (r + dy) * 192;        // staged row base (oct units)
            #pragma unroll
            for (int t = 0; t < 2; ++t) {
                union { uint4 u; bf16x8 v; } bf;
                bf.u = smem[rb + bo[t]];
                acc[dy][t] = __builtin_amdgcn_mfma_f32_16x16x32_bf16(
                                 aF[kc], bf.v, acc[dy][t], 0, 0, 0);
            }
        }
        __syncthreads();
    }

    // ---- epilogue: D[m,n] band -> out channels (all indices unrolled) ----
    const float inv = 1.0f / 128.0f;
    float* ob = out + (size_t)b * 81 * CHS + (size_t)y * Wn + x0s;
    #pragma unroll
    for (int dy = 0; dy < 9; ++dy)
        #pragma unroll
        for (int t = 0; t < 2; ++t)
            #pragma unroll
            for (int reg = 0; reg < 4; ++reg) {
                int mm = quad * 4 + reg;          // D row = first px offset
                int dxc = 16 * t + n16 - mm - 4;  // displacement channel
                if (dxc >= 0 && dxc <= 8)
                    ob[(size_t)(dy * 9 + dxc) * CHS + mm] = acc[dy][t][reg] * inv;
            }
}

// ---------------- fallback (R1 kernel, 135 us) ----------------
constexpr int FTW = 32, FTH = 16, FNT = 128;
constexpr int FHR = FTH + 2, FHC4 = 12, FPITCH = 48;
constexpr int FSLOTS = FHR * FHC4;

__global__ __launch_bounds__(FNT, 2)
void corr3_fb(const float* __restrict__ first, const float* __restrict__ second,
              float* __restrict__ out)
{
    __shared__ float lds[2][FHR * FPITCH];
    const int tid = threadIdx.x;
    const int tx = tid & 7, ty = tid >> 3;
    const int x0 = blockIdx.x * FTW, y0 = blockIdx.y * FTH;
    const int b = blockIdx.z / 3, g = blockIdx.z % 3;
    const int row0 = y0 + 3 * g - 4;
    const int e0 = tid, e1 = tid + FNT;
    const int r0 = e0 / FHC4, c40 = e0 % FHC4;
    const int r1 = e1 / FHC4, c41 = e1 % FHC4;
    const int gy0 = row0 + r0, gy1 = row0 + r1;
    const int gx0 = x0 - 8 + c40 * 4, gx1 = x0 - 8 + c41 * 4;
    const bool s1ok = (e1 < FSLOTS);
    const bool v0 = (gy0 >= 0) & (gy0 < Hn) & (gx0 >= 0) & (gx0 < Wn);
    const bool v1 = s1ok & (gy1 >= 0) & (gy1 < Hn) & (gx1 >= 0) & (gx1 < Wn);
    const int go0 = gy0 * Wn + gx0, go1 = gy1 * Wn + gx1;
    const int lo0 = r0 * FPITCH + c40 * 4, lo1 = r1 * FPITCH + c41 * 4;
    const float* secb = second + (size_t)b * Cn * CHS;
    const float* fb = first + (size_t)b * Cn * CHS + (y0 + ty) * Wn + x0 + tx * 4;
    float acc[3][9][4] = {};
    {
        float4 a0 = make_float4(0, 0, 0, 0), a1 = make_float4(0, 0, 0, 0);
        if (v0) a0 = *(const float4*)(secb + go0);
        if (v1) a1 = *(const float4*)(secb + go1);
        *(float4*)&lds[0][lo0] = a0;
        if (s1ok) *(float4*)&lds[0][lo1] = a1;
    }
    __syncthreads();
    #pragma unroll 1
    for (int c = 0; c < Cn; ++c) {
        const int cur = c & 1;
        float4 nn0 = make_float4(0, 0, 0, 0), nn1 = make_float4(0, 0, 0, 0);
        const bool hn = (c + 1 < Cn);
        if (hn) {
            const float* sp = secb + (c + 1) * CHS;
            if (v0) nn0 = *(const float4*)(sp + go0);
            if (v1) nn1 = *(const float4*)(sp + go1);
        }
        float4 fv = *(const float4*)(fb + c * CHS);
        float fa[4] = {fv.x, fv.y, fv.z, fv.w};
        #pragma unroll
        for (int d = 0; d < 3; ++d) {
            const float* rp = &lds[cur][(ty + d) * FPITCH + tx * 4 + 4];
            float4 w0 = *(const float4*)(rp + 0);
            float4 w1 = *(const float4*)(rp + 4);
            float4 w2 = *(const float4*)(rp + 8);
            float wv[12] = {w0.x, w0.y, w0.z, w0.w, w1.x, w1.y, w1.z, w1.w,
                            w2.x, w2.y, w2.z, w2.w};
            #pragma unroll
            for (int dx = 0; dx < 9; ++dx)
                #pragma unroll
                for (int p = 0; p < 4; ++p)
                    acc[d][dx][p] = fmaf(fa[p], wv[dx + p], acc[d][dx][p]);
        }
        if (hn) {
            *(float4*)&lds[1 - cur][lo0] = nn0;
            if (s1ok) *(float4*)&lds[1 - cur][lo1] = nn1;
        }
        __syncthreads();
    }
    const float invc = 1.0f / (float)Cn;
    float* ob = out + (size_t)b * 81 * CHS + (y0 + ty) * Wn + x0 + tx * 4;
    #pragma unroll
    for (int d = 0; d < 3; ++d)
        #pragma unroll
        for (int dx = 0; dx < 9; ++dx) {
            const int chn = (3 * g + d) * 9 + dx;
            float4 o = make_float4(acc[d][dx][0] * invc, acc[d][dx][1] * invc,
                                   acc[d][dx][2] * invc, acc[d][dx][3] * invc);
            *(float4*)(ob + (size_t)chn * CHS) = o;
        }
}

extern "C" void kernel_launch(void* const* d_in, const int* in_sizes, int n_in,
                              void* d_out, int out_size, void* d_ws, size_t ws_size,
                              hipStream_t stream) {
    const float* first  = (const float*)d_in[0];
    const float* second = (const float*)d_in[1];
    float* out = (float*)d_out;

    if (ws_size >= SECP_BYTES) {
        uint4* secp = (uint4*)d_ws;
        prepass<<<dim3(2, YP, Bn), dim3(256, 1, 1), 0, stream>>>(second, secp);
        corrmfma<<<dim3(Wn / 32, Hn / 8, Bn), dim3(1024, 1, 1), 0, stream>>>(
            first, secp, out);
    } else {
        corr3_fb<<<dim3(Wn / FTW, Hn / FTH, Bn * 3), dim3(FNT, 1, 1), 0, stream>>>(
            first, second, out);
    }
}